// Round 11
// baseline (70.941 us; speedup 1.0000x reference)
//
#include <hip/hip_runtime.h>
#include <math.h>

#define NN 8192
#define NFEAT 512
#define NHID 64
#define NHEADS 4
#define NCLASS 16
#define NEDGE 262144
#define LRELU_ALPHA 0.2f
#define MAXDEG 128

typedef __attribute__((ext_vector_type(8))) short short8;
typedef __attribute__((ext_vector_type(8))) unsigned short ushort8;
typedef __attribute__((ext_vector_type(4))) float f32x4;

__device__ __forceinline__ unsigned short bfr(float f) {
    unsigned int u = __float_as_uint(f);
    u += 0x7fffu + ((u >> 16) & 1u);   // round-to-nearest-even
    return (unsigned short)(u >> 16);
}
__device__ __forceinline__ float bf2f(unsigned short u) {
    return __uint_as_float(((unsigned int)u) << 16);
}

// prep: blocks 0..63 build Wbf (B-fragment-ordered bf16 W1);
// blocks 64..95 zero deg; block 96 packs W2^T -> bf16 [256][16].
__global__ void prep(const float* __restrict__ W1, unsigned short* __restrict__ Wbf,
                     int* __restrict__ deg, const float* __restrict__ W2,
                     unsigned short* __restrict__ W2tb) {
    int b = blockIdx.x, t = threadIdx.x;
    if (b < 64) {
        int idx = b * 256 + t;
        int lane = idx & 63, nt = (idx >> 6) & 15, ks = idx >> 10;
        int tfeat = nt * 16 + (lane & 15);
        int k0 = ks * 32 + (lane >> 4) * 8;
        const float* src = W1 + (size_t)tfeat * NFEAT + k0;
        float4 lo = *(const float4*)src;
        float4 hi = *(const float4*)(src + 4);
        ushort8 v;
        v[0] = bfr(lo.x); v[1] = bfr(lo.y); v[2] = bfr(lo.z); v[3] = bfr(lo.w);
        v[4] = bfr(hi.x); v[5] = bfr(hi.y); v[6] = bfr(hi.z); v[7] = bfr(hi.w);
        *(ushort8*)(Wbf + (size_t)idx * 8) = v;
    } else if (b < 96) {
        deg[(b - 64) * 256 + t] = 0;
    } else {
#pragma unroll
        for (int c = 0; c < NCLASS; c++)
            W2tb[t * 16 + c] = bfr(W2[c * 256 + t]);   // reads coalesced per c
    }
}

// gemm1c: blocks 0..255 = MFMA gemm1, 32 nodes/block (B-frags reused across
// two node-tiles -> W L2 traffic halved); blocks 256..1279 = dense-bucket CSR.
__global__ void gemm1c(const float* __restrict__ x, const unsigned short* __restrict__ Wbf,
                       const float* __restrict__ b1, unsigned short* __restrict__ h1b,
                       const float* __restrict__ a1, float* __restrict__ as1,
                       float* __restrict__ at1, const int* __restrict__ src_e,
                       const int* __restrict__ tgt_e, int* __restrict__ deg,
                       int* __restrict__ dense) {
    __shared__ __align__(16) unsigned short xs[32 * 512];   // 32 KB, XOR-swizzled rows
    int t = threadIdx.x;
    if (blockIdx.x >= 256) {
        int k = (blockIdx.x - 256) * 256 + t;   // 1024*256 == NEDGE exactly
        int s = src_e[k];
        int slot = atomicAdd(&deg[s], 1);
        if (slot < MAXDEG) dense[(size_t)s * MAXDEG + slot] = tgt_e[k];
        return;
    }
    int n0 = blockIdx.x * 32;
    const float4* xv = (const float4*)(x + (size_t)n0 * NFEAT);
#pragma unroll
    for (int i = 0; i < 8; i++) {
        int g = i * 256 + t;          // 2048 groups of 8 bf16 (16 B)
        int row = g >> 6;
        int k0 = (g & 63) * 8;
        float4 lo = xv[g * 2];
        float4 hi = xv[g * 2 + 1];
        ushort8 v;
        v[0] = bfr(lo.x); v[1] = bfr(lo.y); v[2] = bfr(lo.z); v[3] = bfr(lo.w);
        v[4] = bfr(hi.x); v[5] = bfr(hi.y); v[6] = bfr(hi.z); v[7] = bfr(hi.w);
        int byte = (k0 * 2) ^ ((row & 7) << 4);
        *(ushort8*)((char*)xs + row * 1024 + byte) = v;
    }
    __syncthreads();
    int w = t >> 6, lane = t & 63;
    int arow = lane & 15, kg = lane >> 4;
    f32x4 acc[2][4];
#pragma unroll
    for (int m = 0; m < 2; m++)
#pragma unroll
        for (int j = 0; j < 4; j++) acc[m][j] = (f32x4){0.f, 0.f, 0.f, 0.f};
    const unsigned short* wb = Wbf + ((size_t)(w * 4) * 64 + lane) * 8;
    int abase0 = arow * 1024;
    int abase1 = (16 + arow) * 1024;
    int aswz = (arow & 7) << 4;
    for (int ks = 0; ks < 16; ks++) {
        int aoff = (ks * 64 + kg * 16) ^ aswz;
        short8 af0 = *(const short8*)((const char*)xs + abase0 + aoff);
        short8 af1 = *(const short8*)((const char*)xs + abase1 + aoff);
#pragma unroll
        for (int j = 0; j < 4; j++) {
            short8 bfrag = *(const short8*)(wb + j * 512);
            acc[0][j] = __builtin_amdgcn_mfma_f32_16x16x32_bf16(af0, bfrag, acc[0][j], 0, 0, 0);
            acc[1][j] = __builtin_amdgcn_mfma_f32_16x16x32_bf16(af1, bfrag, acc[1][j], 0, 0, 0);
        }
        wb += 8192;
    }
    int g4 = lane >> 4, cf = lane & 15;
#pragma unroll
    for (int m = 0; m < 2; m++) {
        float p1[4] = {0.f, 0.f, 0.f, 0.f}, p2[4] = {0.f, 0.f, 0.f, 0.f};
#pragma unroll
        for (int j = 0; j < 4; j++) {
            int d = j * 16 + cf;
            float bias = b1[w * 64 + d];
            float c1 = a1[w * 2 * NHID + d];
            float c2 = a1[w * 2 * NHID + NHID + d];
#pragma unroll
            for (int r = 0; r < 4; r++) {
                int n = n0 + m * 16 + g4 * 4 + r;
                float v = acc[m][j][r] + bias;
                h1b[((size_t)w * NN + n) * NHID + d] = bfr(v);
                p1[r] += v * c1;
                p2[r] += v * c2;
            }
        }
#pragma unroll
        for (int r = 0; r < 4; r++) {
            float s1 = p1[r], s2 = p2[r];
#pragma unroll
            for (int o = 8; o >= 1; o >>= 1) {
                s1 += __shfl_xor(s1, o);
                s2 += __shfl_xor(s2, o);
            }
            if (cf == 0) {
                int n = n0 + m * 16 + g4 * 4 + r;
                as1[n * 4 + w] = s1;
                at1[n * 4 + w] = s2;
            }
        }
    }
}

// agg1f: one WAVE per row, no LDS/syncthreads on fast path. Softmax + gather
// + fused gemm2 epilogue (W2^T bf16 frags loaded from L2 into registers).
// Writes packed (tgt | mult<<16, -1 dup) back into dense for agg2.
__global__ void agg1f(const unsigned short* __restrict__ h1b, const float* __restrict__ as1,
                      const float* __restrict__ at1, const int* __restrict__ degv,
                      int* __restrict__ dense, const unsigned short* __restrict__ W2tb,
                      const float* __restrict__ b2g, const float* __restrict__ a2,
                      float* __restrict__ h2, float* __restrict__ as2,
                      float* __restrict__ at2) {
    __shared__ int tsf[4][MAXDEG];            // fallback only
    __shared__ float psf[4][NHEADS][MAXDEG];  // fallback only
    int tid = threadIdx.x;
    int wv = tid >> 6, lane = tid & 63;
    int n = blockIdx.x * 4 + wv;
    int deg = degv[n];
    if (deg > MAXDEG) deg = MAXDEG;
    int eg = lane >> 3, dg = lane & 7;
    int* drow = dense + (size_t)n * MAXDEG;
    float outv[4] = {0.f, 0.f, 0.f, 0.f};
    if (deg > 0 && deg <= 64) {
        float4 asv = *(const float4*)(as1 + n * 4);
        int t = -1 - lane;
        float ea[4] = {0.f, 0.f, 0.f, 0.f};
        if (lane < deg) {
            t = drow[lane];
            float4 atv = *(const float4*)(at1 + t * 4);
            float e0 = asv.x + atv.x, e1 = asv.y + atv.y;
            float e2 = asv.z + atv.z, e3 = asv.w + atv.w;
            ea[0] = e0 > 0.f ? e0 : LRELU_ALPHA * e0;
            ea[1] = e1 > 0.f ? e1 : LRELU_ALPHA * e1;
            ea[2] = e2 > 0.f ? e2 : LRELU_ALPHA * e2;
            ea[3] = e3 > 0.f ? e3 : LRELU_ALPHA * e3;
        }
        int mult = 1;
        bool skip = false;
        for (int k = 1; k < 64; k++) {
            int idx = (lane + k) & 63;
            int to = __shfl(t, idx);
            if (to == t) { mult++; if (idx < lane) skip = true; }
        }
        if (lane < deg) drow[lane] = skip ? -1 : (t | (mult << 16));
        bool valid = (lane < deg) && !skip;
        float mf = (float)mult;
        int tj[8];
#pragma unroll
        for (int i = 0; i < 8; i++) {
            int tv = __shfl(t, i * 8 + eg);
            tj[i] = tv < 0 ? 0 : tv;
        }
        bool b2 = (eg & 4) != 0, b1 = (eg & 2) != 0, b0 = (eg & 1) != 0;
#pragma unroll
        for (int h = 0; h < 4; h++) {
            float p = valid ? mf * ea[h] : -INFINITY;
            float m = p;
#pragma unroll
            for (int o = 32; o >= 1; o >>= 1) m = fmaxf(m, __shfl_xor(m, o));
            float pe = expf(p - m);
            float s = pe;
#pragma unroll
            for (int o = 32; o >= 1; o >>= 1) s += __shfl_xor(s, o);
            const unsigned short* hb = h1b + (size_t)h * NN * NHID;
            float acc[8] = {0.f, 0.f, 0.f, 0.f, 0.f, 0.f, 0.f, 0.f};
#pragma unroll
            for (int i = 0; i < 8; i++) {
                float pj = __shfl(pe, i * 8 + eg);
                ushort8 hv = *(const ushort8*)(hb + (size_t)tj[i] * NHID + dg * 8);
#pragma unroll
                for (int q = 0; q < 8; q++) acc[q] += pj * bf2f(hv[q]);
            }
            float k4[4], k2[2], r;
#pragma unroll
            for (int q = 0; q < 4; q++) {
                float keep = b2 ? acc[4 + q] : acc[q];
                float send = b2 ? acc[q] : acc[4 + q];
                k4[q] = keep + __shfl_xor(send, 32);
            }
#pragma unroll
            for (int q = 0; q < 2; q++) {
                float keep = b1 ? k4[2 + q] : k4[q];
                float send = b1 ? k4[q] : k4[2 + q];
                k2[q] = keep + __shfl_xor(send, 16);
            }
            {
                float keep = b0 ? k2[1] : k2[0];
                float send = b0 ? k2[0] : k2[1];
                r = keep + __shfl_xor(send, 8);
            }
            float v = r / s;
            outv[h] = v > 0.f ? v : (expf(v) - 1.f);   // ELU
        }
    } else if (deg > 64) {
        // ---- wave-local LDS fallback (statistically never taken) ----
        float4 asv = *(const float4*)(as1 + n * 4);
        int* ts = tsf[wv];
        for (int j = lane; j < deg; j += 64) {
            int tv = drow[j];
            ts[j] = tv;
            float4 atv = *(const float4*)(at1 + tv * 4);
            float e0 = asv.x + atv.x, e1 = asv.y + atv.y;
            float e2 = asv.z + atv.z, e3 = asv.w + atv.w;
            psf[wv][0][j] = e0 > 0.f ? e0 : LRELU_ALPHA * e0;
            psf[wv][1][j] = e1 > 0.f ? e1 : LRELU_ALPHA * e1;
            psf[wv][2][j] = e2 > 0.f ? e2 : LRELU_ALPHA * e2;
            psf[wv][3][j] = e3 > 0.f ? e3 : LRELU_ALPHA * e3;
        }
        for (int j = lane; j < deg; j += 64) {
            int tjv = ts[j];
            int m = 1;
            bool skip = false;
            for (int j2 = 0; j2 < deg; j2++) {
                if (j2 == j) continue;
                if (ts[j2] == tjv) {
                    if (j2 < j) { skip = true; break; }
                    m++;
                }
            }
            if (skip) {
                psf[wv][0][j] = -INFINITY; psf[wv][1][j] = -INFINITY;
                psf[wv][2][j] = -INFINITY; psf[wv][3][j] = -INFINITY;
                drow[j] = -1;
            } else {
                float mf = (float)m;
                psf[wv][0][j] *= mf; psf[wv][1][j] *= mf;
                psf[wv][2][j] *= mf; psf[wv][3][j] *= mf;
                drow[j] = tjv | (m << 16);
            }
        }
        for (int h = 0; h < 4; h++) {
            float m = -INFINITY;
            for (int j = lane; j < deg; j += 64) m = fmaxf(m, psf[wv][h][j]);
#pragma unroll
            for (int o = 32; o >= 1; o >>= 1) m = fmaxf(m, __shfl_xor(m, o));
            float s = 0.f;
            for (int j = lane; j < deg; j += 64) {
                float pe = expf(psf[wv][h][j] - m);
                psf[wv][h][j] = pe;
                s += pe;
            }
#pragma unroll
            for (int o = 32; o >= 1; o >>= 1) s += __shfl_xor(s, o);
            const unsigned short* hb = h1b + (size_t)h * NN * NHID;
            float acc[8] = {0.f, 0.f, 0.f, 0.f, 0.f, 0.f, 0.f, 0.f};
            for (int j = eg; j < deg; j += 8) {
                float pj = psf[wv][h][j];
                int tjv = ts[j];
                ushort8 hv = *(const ushort8*)(hb + (size_t)tjv * NHID + dg * 8);
#pragma unroll
                for (int q = 0; q < 8; q++) acc[q] += pj * bf2f(hv[q]);
            }
            bool b2 = (eg & 4) != 0, b1 = (eg & 2) != 0, b0 = (eg & 1) != 0;
            float k4[4], k2[2], r;
#pragma unroll
            for (int q = 0; q < 4; q++) {
                float keep = b2 ? acc[4 + q] : acc[q];
                float send = b2 ? acc[q] : acc[4 + q];
                k4[q] = keep + __shfl_xor(send, 32);
            }
#pragma unroll
            for (int q = 0; q < 2; q++) {
                float keep = b1 ? k4[2 + q] : k4[q];
                float send = b1 ? k4[q] : k4[2 + q];
                k2[q] = keep + __shfl_xor(send, 16);
            }
            {
                float keep = b0 ? k2[1] : k2[0];
                float send = b0 ? k2[0] : k2[1];
                r = keep + __shfl_xor(send, 8);
            }
            float v = r / s;
            outv[h] = v > 0.f ? v : (expf(v) - 1.f);
        }
    }
    // ---- fused gemm2 epilogue: W2^T frags from L2, butterfly reduce ----
    float cp[16];
#pragma unroll
    for (int c = 0; c < 16; c++) cp[c] = 0.f;
#pragma unroll
    for (int h = 0; h < 4; h++) {
        const unsigned short* wrow = W2tb + (h * 64 + dg * 8 + eg) * 16;
        ushort8 wlo = *(const ushort8*)wrow;
        ushort8 whi = *(const ushort8*)(wrow + 8);
        float ov = outv[h];
#pragma unroll
        for (int c = 0; c < 8; c++) {
            cp[c] = fmaf(ov, bf2f(wlo[c]), cp[c]);
            cp[8 + c] = fmaf(ov, bf2f(whi[c]), cp[8 + c]);
        }
    }
    bool t0 = (lane & 1) != 0, t1 = (lane & 2) != 0, t2 = (lane & 4) != 0, t3 = (lane & 8) != 0;
    float p8[8];
#pragma unroll
    for (int q = 0; q < 8; q++) {
        float keep = t0 ? cp[8 + q] : cp[q];
        float send = t0 ? cp[q] : cp[8 + q];
        p8[q] = keep + __shfl_xor(send, 1);
    }
    float p4[4];
#pragma unroll
    for (int q = 0; q < 4; q++) {
        float keep = t1 ? p8[4 + q] : p8[q];
        float send = t1 ? p8[q] : p8[4 + q];
        p4[q] = keep + __shfl_xor(send, 2);
    }
    float p2[2];
#pragma unroll
    for (int q = 0; q < 2; q++) {
        float keep = t2 ? p4[2 + q] : p4[q];
        float send = t2 ? p4[q] : p4[2 + q];
        p2[q] = keep + __shfl_xor(send, 4);
    }
    float r = (t3 ? p2[1] : p2[0]) + __shfl_xor(t3 ? p2[0] : p2[1], 8);
    r += __shfl_xor(r, 16);
    r += __shfl_xor(r, 32);
    int c = ((lane & 1) << 3) | ((lane & 2) << 1) | ((lane & 4) >> 1) | ((lane & 8) >> 3);
    float rr = r + b2g[c];
    if (lane < 16) h2[(size_t)n * NCLASS + c] = rr;
    float q1 = rr * a2[c], q2 = rr * a2[NCLASS + c];
#pragma unroll
    for (int o = 1; o < 64; o <<= 1) {
        q1 += __shfl_xor(q1, o);
        q2 += __shfl_xor(q2, o);
    }
    if (lane == 0) { as2[n] = q1 * 0.25f; at2[n] = q2 * 0.25f; }
}

// agg2: one WAVE per row, packed dense (no dup pass), fused log_softmax.
__global__ void agg2(const float* __restrict__ h2, const float* __restrict__ as2,
                     const float* __restrict__ at2, const int* __restrict__ degv,
                     const int* __restrict__ dense, float* __restrict__ out) {
    __shared__ int tf[4][MAXDEG];
    __shared__ float pf[4][MAXDEG];
    int wv = threadIdx.x >> 6, lane = threadIdx.x & 63;
    int n = blockIdx.x * 4 + wv;
    int deg = degv[n];
    if (deg > MAXDEG) deg = MAXDEG;
    if (deg == 0) {
        if (lane < NCLASS) out[(size_t)n * NCLASS + lane] = -logf((float)NCLASS);
        return;
    }
    const int* drow = dense + (size_t)n * MAXDEG;
    float asvn = as2[n];
    int jg = lane >> 2, cq = lane & 3;
    if (deg <= 64) {
        int pk = (lane < deg) ? drow[lane] : -1;
        int t = 0;
        float p = -INFINITY;
        if (pk >= 0) {
            t = pk & 0xFFFF;
            float e = asvn + at2[t];
            e = e > 0.f ? e : LRELU_ALPHA * e;
            p = (float)(pk >> 16) * e;
        }
        float m = p;
#pragma unroll
        for (int o = 32; o >= 1; o >>= 1) m = fmaxf(m, __shfl_xor(m, o));
        float pe = expf(p - m);
        float s = pe;
#pragma unroll
        for (int o = 32; o >= 1; o >>= 1) s += __shfl_xor(s, o);
        float4 a4 = {0.f, 0.f, 0.f, 0.f};
#pragma unroll
        for (int i = 0; i < 4; i++) {
            int j = i * 16 + jg;
            float pj = __shfl(pe, j);
            int tjv = __shfl(t, j);
            float4 hv = *(const float4*)(h2 + (size_t)tjv * NCLASS + cq * 4);
            a4.x += pj * hv.x; a4.y += pj * hv.y;
            a4.z += pj * hv.z; a4.w += pj * hv.w;
        }
#pragma unroll
        for (int o = 4; o <= 32; o <<= 1) {
            a4.x += __shfl_xor(a4.x, o);
            a4.y += __shfl_xor(a4.y, o);
            a4.z += __shfl_xor(a4.z, o);
            a4.w += __shfl_xor(a4.w, o);
        }
        float inv = 1.f / s;
        float4 v4 = {a4.x * inv, a4.y * inv, a4.z * inv, a4.w * inv};
        float mm = fmaxf(fmaxf(v4.x, v4.y), fmaxf(v4.z, v4.w));
        mm = fmaxf(mm, __shfl_xor(mm, 1));
        mm = fmaxf(mm, __shfl_xor(mm, 2));
        float se = expf(v4.x - mm) + expf(v4.y - mm) + expf(v4.z - mm) + expf(v4.w - mm);
        se += __shfl_xor(se, 1);
        se += __shfl_xor(se, 2);
        float lse = mm + logf(se);
        if (jg == 0) {
            float4 o4 = {v4.x - lse, v4.y - lse, v4.z - lse, v4.w - lse};
            *(float4*)(out + (size_t)n * NCLASS + cq * 4) = o4;
        }
    } else {
        for (int j = lane; j < deg; j += 64) {
            int pk = drow[j];
            if (pk < 0) {
                tf[wv][j] = 0;
                pf[wv][j] = -INFINITY;
            } else {
                int t = pk & 0xFFFF;
                tf[wv][j] = t;
                float e = asvn + at2[t];
                e = e > 0.f ? e : LRELU_ALPHA * e;
                pf[wv][j] = (float)(pk >> 16) * e;
            }
        }
        float m = -INFINITY;
        for (int j = lane; j < deg; j += 64) m = fmaxf(m, pf[wv][j]);
#pragma unroll
        for (int o = 32; o >= 1; o >>= 1) m = fmaxf(m, __shfl_xor(m, o));
        float s = 0.f;
        for (int j = lane; j < deg; j += 64) {
            float pe = expf(pf[wv][j] - m);
            pf[wv][j] = pe;
            s += pe;
        }
#pragma unroll
        for (int o = 32; o >= 1; o >>= 1) s += __shfl_xor(s, o);
        float4 a4 = {0.f, 0.f, 0.f, 0.f};
        for (int j = jg; j < deg; j += 16) {
            float pj = pf[wv][j];
            float4 hv = *(const float4*)(h2 + (size_t)tf[wv][j] * NCLASS + cq * 4);
            a4.x += pj * hv.x; a4.y += pj * hv.y;
            a4.z += pj * hv.z; a4.w += pj * hv.w;
        }
#pragma unroll
        for (int o = 4; o <= 32; o <<= 1) {
            a4.x += __shfl_xor(a4.x, o);
            a4.y += __shfl_xor(a4.y, o);
            a4.z += __shfl_xor(a4.z, o);
            a4.w += __shfl_xor(a4.w, o);
        }
        float inv = 1.f / s;
        float4 v4 = {a4.x * inv, a4.y * inv, a4.z * inv, a4.w * inv};
        float mm = fmaxf(fmaxf(v4.x, v4.y), fmaxf(v4.z, v4.w));
        mm = fmaxf(mm, __shfl_xor(mm, 1));
        mm = fmaxf(mm, __shfl_xor(mm, 2));
        float se = expf(v4.x - mm) + expf(v4.y - mm) + expf(v4.z - mm) + expf(v4.w - mm);
        se += __shfl_xor(se, 1);
        se += __shfl_xor(se, 2);
        float lse = mm + logf(se);
        if (jg == 0) {
            float4 o4 = {v4.x - lse, v4.y - lse, v4.z - lse, v4.w - lse};
            *(float4*)(out + (size_t)n * NCLASS + cq * 4) = o4;
        }
    }
}

extern "C" void kernel_launch(void* const* d_in, const int* in_sizes, int n_in,
                              void* d_out, int out_size, void* d_ws, size_t ws_size,
                              hipStream_t stream) {
    const float* x  = (const float*)d_in[0];
    const int* el   = (const int*)d_in[1];
    const float* W1 = (const float*)d_in[2];
    const float* b1 = (const float*)d_in[3];
    const float* a1 = (const float*)d_in[4];
    const float* W2 = (const float*)d_in[5];
    const float* b2 = (const float*)d_in[6];
    const float* a2 = (const float*)d_in[7];
    float* out = (float*)d_out;

    unsigned short* h1b = (unsigned short*)d_ws;  // 4*8192*64 bf16 = 4 MB
    float* h2   = (float*)(h1b + 2097152);        // 8192*16 fp32
    float* as1  = h2 + 131072;                    // [n][4]
    float* at1  = as1 + 32768;                    // [n][4]
    float* as2  = at1 + 32768;
    float* at2  = as2 + 8192;
    int* deg    = (int*)(at2 + 8192);             // 8192
    int* dense  = deg + 8192;                     // 8192*128 = 4 MB
    unsigned short* Wbf  = (unsigned short*)(dense + 8192 * MAXDEG);  // 256 KB
    unsigned short* W2tb = Wbf + 131072;          // 256*16 bf16 = 8 KB

    const int* src = el;
    const int* tgt = el + NEDGE;

    prep<<<97, 256, 0, stream>>>(W1, Wbf, deg, W2, W2tb);
    gemm1c<<<1280, 256, 0, stream>>>(x, Wbf, b1, h1b, a1, as1, at1, src, tgt, deg, dense);
    agg1f<<<NN / 4, 256, 0, stream>>>(h1b, as1, at1, deg, dense, W2tb, b2, a2, h2, as2, at2);
    agg2<<<NN / 4, 256, 0, stream>>>(h2, as2, at2, deg, dense, out);
}

// Round 12
// 64.791 us; speedup vs baseline: 1.0949x; 1.0949x over previous
//
#include <hip/hip_runtime.h>
#include <math.h>

#define NN 8192
#define NFEAT 512
#define NHID 64
#define NHEADS 4
#define NCLASS 16
#define NEDGE 262144
#define LRELU_ALPHA 0.2f
#define MAXDEG 128

typedef __attribute__((ext_vector_type(8))) short short8;
typedef __attribute__((ext_vector_type(8))) unsigned short ushort8;
typedef __attribute__((ext_vector_type(4))) float f32x4;

__device__ __forceinline__ unsigned short bfr(float f) {
    unsigned int u = __float_as_uint(f);
    u += 0x7fffu + ((u >> 16) & 1u);   // round-to-nearest-even
    return (unsigned short)(u >> 16);
}
__device__ __forceinline__ float bf2f(unsigned short u) {
    return __uint_as_float(((unsigned int)u) << 16);
}

// prep: blocks 0..63 build Wbf (B-fragment-ordered bf16 W1);
// blocks 64..95 zero deg; block 96 packs W2^T -> bf16 [256][16].
__global__ void prep(const float* __restrict__ W1, unsigned short* __restrict__ Wbf,
                     int* __restrict__ deg, const float* __restrict__ W2,
                     unsigned short* __restrict__ W2tb) {
    int b = blockIdx.x, t = threadIdx.x;
    if (b < 64) {
        int idx = b * 256 + t;
        int lane = idx & 63, nt = (idx >> 6) & 15, ks = idx >> 10;
        int tfeat = nt * 16 + (lane & 15);
        int k0 = ks * 32 + (lane >> 4) * 8;
        const float* src = W1 + (size_t)tfeat * NFEAT + k0;
        float4 lo = *(const float4*)src;
        float4 hi = *(const float4*)(src + 4);
        ushort8 v;
        v[0] = bfr(lo.x); v[1] = bfr(lo.y); v[2] = bfr(lo.z); v[3] = bfr(lo.w);
        v[4] = bfr(hi.x); v[5] = bfr(hi.y); v[6] = bfr(hi.z); v[7] = bfr(hi.w);
        *(ushort8*)(Wbf + (size_t)idx * 8) = v;
    } else if (b < 96) {
        deg[(b - 64) * 256 + t] = 0;
    } else {
#pragma unroll
        for (int c = 0; c < NCLASS; c++)
            W2tb[t * 16 + c] = bfr(W2[c * 256 + t]);   // reads coalesced per c
    }
}

// gemm1c: blocks 0..511 = MFMA gemm1 (h1b bf16 + fused as1/at1 scores);
// blocks 512..1535 = dense-bucket CSR build (replaces count+scan+fill).
__global__ void gemm1c(const float* __restrict__ x, const unsigned short* __restrict__ Wbf,
                       const float* __restrict__ b1, unsigned short* __restrict__ h1b,
                       const float* __restrict__ a1, float* __restrict__ as1,
                       float* __restrict__ at1, const int* __restrict__ src_e,
                       const int* __restrict__ tgt_e, int* __restrict__ deg,
                       int* __restrict__ dense) {
    __shared__ __align__(16) unsigned short xs[16 * 512];   // 16 KB, XOR-swizzled rows
    int t = threadIdx.x;
    if (blockIdx.x >= 512) {
        int k = (blockIdx.x - 512) * 256 + t;   // 1024*256 == NEDGE exactly
        int s = src_e[k];
        int slot = atomicAdd(&deg[s], 1);
        if (slot < MAXDEG) dense[(size_t)s * MAXDEG + slot] = tgt_e[k];
        return;
    }
    int n0 = blockIdx.x * 16;
    const float4* xv = (const float4*)(x + (size_t)n0 * NFEAT);
#pragma unroll
    for (int i = 0; i < 4; i++) {
        int g = i * 256 + t;
        int row = g >> 6;
        int k0 = (g & 63) * 8;
        float4 lo = xv[g * 2];
        float4 hi = xv[g * 2 + 1];
        ushort8 v;
        v[0] = bfr(lo.x); v[1] = bfr(lo.y); v[2] = bfr(lo.z); v[3] = bfr(lo.w);
        v[4] = bfr(hi.x); v[5] = bfr(hi.y); v[6] = bfr(hi.z); v[7] = bfr(hi.w);
        int byte = (k0 * 2) ^ ((row & 7) << 4);
        *(ushort8*)((char*)xs + row * 1024 + byte) = v;
    }
    __syncthreads();
    int w = t >> 6, lane = t & 63;
    int arow = lane & 15, kg = lane >> 4;
    f32x4 acc[4];
#pragma unroll
    for (int j = 0; j < 4; j++) acc[j] = (f32x4){0.f, 0.f, 0.f, 0.f};
    const unsigned short* wb = Wbf + ((size_t)(w * 4) * 64 + lane) * 8;
    int abase = arow * 1024;
    int aswz = (arow & 7) << 4;
    for (int ks = 0; ks < 16; ks++) {
        short8 afrag = *(const short8*)((const char*)xs + abase + ((ks * 64 + kg * 16) ^ aswz));
#pragma unroll
        for (int j = 0; j < 4; j++) {
            short8 bfrag = *(const short8*)(wb + j * 512);
            acc[j] = __builtin_amdgcn_mfma_f32_16x16x32_bf16(afrag, bfrag, acc[j], 0, 0, 0);
        }
        wb += 8192;
    }
    int g4 = lane >> 4, cf = lane & 15;
    float p1[4] = {0.f, 0.f, 0.f, 0.f}, p2[4] = {0.f, 0.f, 0.f, 0.f};
#pragma unroll
    for (int j = 0; j < 4; j++) {
        int d = j * 16 + cf;
        float bias = b1[w * 64 + d];
        float c1 = a1[w * 2 * NHID + d];
        float c2 = a1[w * 2 * NHID + NHID + d];
#pragma unroll
        for (int r = 0; r < 4; r++) {
            int n = n0 + g4 * 4 + r;
            float v = acc[j][r] + bias;
            h1b[((size_t)w * NN + n) * NHID + d] = bfr(v);
            p1[r] += v * c1;
            p2[r] += v * c2;
        }
    }
#pragma unroll
    for (int r = 0; r < 4; r++) {
        float s1 = p1[r], s2 = p2[r];
#pragma unroll
        for (int o = 8; o >= 1; o >>= 1) {
            s1 += __shfl_xor(s1, o);
            s2 += __shfl_xor(s2, o);
        }
        if (cf == 0) {
            int n = n0 + g4 * 4 + r;
            as1[n * 4 + w] = s1;
            at1[n * 4 + w] = s2;
        }
    }
}

// agg1f: one WAVE per row, no LDS/syncthreads on fast path. Softmax + gather
// + fused gemm2 epilogue (W2^T bf16 frags loaded from L2 into registers).
// Writes packed (tgt | mult<<16, -1 dup) back into dense for agg2.
__global__ void agg1f(const unsigned short* __restrict__ h1b, const float* __restrict__ as1,
                      const float* __restrict__ at1, const int* __restrict__ degv,
                      int* __restrict__ dense, const unsigned short* __restrict__ W2tb,
                      const float* __restrict__ b2g, const float* __restrict__ a2,
                      float* __restrict__ h2, float* __restrict__ as2,
                      float* __restrict__ at2) {
    __shared__ int tsf[4][MAXDEG];            // fallback only
    __shared__ float psf[4][NHEADS][MAXDEG];  // fallback only
    int tid = threadIdx.x;
    int wv = tid >> 6, lane = tid & 63;
    int n = blockIdx.x * 4 + wv;
    int deg = degv[n];
    if (deg > MAXDEG) deg = MAXDEG;
    int eg = lane >> 3, dg = lane & 7;
    int* drow = dense + (size_t)n * MAXDEG;
    float outv[4] = {0.f, 0.f, 0.f, 0.f};
    if (deg > 0 && deg <= 64) {
        float4 asv = *(const float4*)(as1 + n * 4);
        int t = -1 - lane;
        float ea[4] = {0.f, 0.f, 0.f, 0.f};
        if (lane < deg) {
            t = drow[lane];
            float4 atv = *(const float4*)(at1 + t * 4);
            float e0 = asv.x + atv.x, e1 = asv.y + atv.y;
            float e2 = asv.z + atv.z, e3 = asv.w + atv.w;
            ea[0] = e0 > 0.f ? e0 : LRELU_ALPHA * e0;
            ea[1] = e1 > 0.f ? e1 : LRELU_ALPHA * e1;
            ea[2] = e2 > 0.f ? e2 : LRELU_ALPHA * e2;
            ea[3] = e3 > 0.f ? e3 : LRELU_ALPHA * e3;
        }
        int mult = 1;
        bool skip = false;
        for (int k = 1; k < 64; k++) {
            int idx = (lane + k) & 63;
            int to = __shfl(t, idx);
            if (to == t) { mult++; if (idx < lane) skip = true; }
        }
        if (lane < deg) drow[lane] = skip ? -1 : (t | (mult << 16));
        bool valid = (lane < deg) && !skip;
        float mf = (float)mult;
        int tj[8];
#pragma unroll
        for (int i = 0; i < 8; i++) {
            int tv = __shfl(t, i * 8 + eg);
            tj[i] = tv < 0 ? 0 : tv;
        }
        bool b2 = (eg & 4) != 0, b1 = (eg & 2) != 0, b0 = (eg & 1) != 0;
#pragma unroll
        for (int h = 0; h < 4; h++) {
            float p = valid ? mf * ea[h] : -INFINITY;
            float m = p;
#pragma unroll
            for (int o = 32; o >= 1; o >>= 1) m = fmaxf(m, __shfl_xor(m, o));
            float pe = expf(p - m);
            float s = pe;
#pragma unroll
            for (int o = 32; o >= 1; o >>= 1) s += __shfl_xor(s, o);
            const unsigned short* hb = h1b + (size_t)h * NN * NHID;
            float acc[8] = {0.f, 0.f, 0.f, 0.f, 0.f, 0.f, 0.f, 0.f};
#pragma unroll
            for (int i = 0; i < 8; i++) {
                float pj = __shfl(pe, i * 8 + eg);
                ushort8 hv = *(const ushort8*)(hb + (size_t)tj[i] * NHID + dg * 8);
#pragma unroll
                for (int q = 0; q < 8; q++) acc[q] += pj * bf2f(hv[q]);
            }
            float k4[4], k2[2], r;
#pragma unroll
            for (int q = 0; q < 4; q++) {
                float keep = b2 ? acc[4 + q] : acc[q];
                float send = b2 ? acc[q] : acc[4 + q];
                k4[q] = keep + __shfl_xor(send, 32);
            }
#pragma unroll
            for (int q = 0; q < 2; q++) {
                float keep = b1 ? k4[2 + q] : k4[q];
                float send = b1 ? k4[q] : k4[2 + q];
                k2[q] = keep + __shfl_xor(send, 16);
            }
            {
                float keep = b0 ? k2[1] : k2[0];
                float send = b0 ? k2[0] : k2[1];
                r = keep + __shfl_xor(send, 8);
            }
            float v = r / s;
            outv[h] = v > 0.f ? v : (expf(v) - 1.f);   // ELU
        }
    } else if (deg > 64) {
        // ---- wave-local LDS fallback (statistically never taken) ----
        float4 asv = *(const float4*)(as1 + n * 4);
        int* ts = tsf[wv];
        for (int j = lane; j < deg; j += 64) {
            int tv = drow[j];
            ts[j] = tv;
            float4 atv = *(const float4*)(at1 + tv * 4);
            float e0 = asv.x + atv.x, e1 = asv.y + atv.y;
            float e2 = asv.z + atv.z, e3 = asv.w + atv.w;
            psf[wv][0][j] = e0 > 0.f ? e0 : LRELU_ALPHA * e0;
            psf[wv][1][j] = e1 > 0.f ? e1 : LRELU_ALPHA * e1;
            psf[wv][2][j] = e2 > 0.f ? e2 : LRELU_ALPHA * e2;
            psf[wv][3][j] = e3 > 0.f ? e3 : LRELU_ALPHA * e3;
        }
        for (int j = lane; j < deg; j += 64) {
            int tjv = ts[j];
            int m = 1;
            bool skip = false;
            for (int j2 = 0; j2 < deg; j2++) {
                if (j2 == j) continue;
                if (ts[j2] == tjv) {
                    if (j2 < j) { skip = true; break; }
                    m++;
                }
            }
            if (skip) {
                psf[wv][0][j] = -INFINITY; psf[wv][1][j] = -INFINITY;
                psf[wv][2][j] = -INFINITY; psf[wv][3][j] = -INFINITY;
                drow[j] = -1;
            } else {
                float mf = (float)m;
                psf[wv][0][j] *= mf; psf[wv][1][j] *= mf;
                psf[wv][2][j] *= mf; psf[wv][3][j] *= mf;
                drow[j] = tjv | (m << 16);
            }
        }
        for (int h = 0; h < 4; h++) {
            float m = -INFINITY;
            for (int j = lane; j < deg; j += 64) m = fmaxf(m, psf[wv][h][j]);
#pragma unroll
            for (int o = 32; o >= 1; o >>= 1) m = fmaxf(m, __shfl_xor(m, o));
            float s = 0.f;
            for (int j = lane; j < deg; j += 64) {
                float pe = expf(psf[wv][h][j] - m);
                psf[wv][h][j] = pe;
                s += pe;
            }
#pragma unroll
            for (int o = 32; o >= 1; o >>= 1) s += __shfl_xor(s, o);
            const unsigned short* hb = h1b + (size_t)h * NN * NHID;
            float acc[8] = {0.f, 0.f, 0.f, 0.f, 0.f, 0.f, 0.f, 0.f};
            for (int j = eg; j < deg; j += 8) {
                float pj = psf[wv][h][j];
                int tjv = ts[j];
                ushort8 hv = *(const ushort8*)(hb + (size_t)tjv * NHID + dg * 8);
#pragma unroll
                for (int q = 0; q < 8; q++) acc[q] += pj * bf2f(hv[q]);
            }
            bool b2 = (eg & 4) != 0, b1 = (eg & 2) != 0, b0 = (eg & 1) != 0;
            float k4[4], k2[2], r;
#pragma unroll
            for (int q = 0; q < 4; q++) {
                float keep = b2 ? acc[4 + q] : acc[q];
                float send = b2 ? acc[q] : acc[4 + q];
                k4[q] = keep + __shfl_xor(send, 32);
            }
#pragma unroll
            for (int q = 0; q < 2; q++) {
                float keep = b1 ? k4[2 + q] : k4[q];
                float send = b1 ? k4[q] : k4[2 + q];
                k2[q] = keep + __shfl_xor(send, 16);
            }
            {
                float keep = b0 ? k2[1] : k2[0];
                float send = b0 ? k2[0] : k2[1];
                r = keep + __shfl_xor(send, 8);
            }
            float v = r / s;
            outv[h] = v > 0.f ? v : (expf(v) - 1.f);
        }
    }
    // ---- fused gemm2 epilogue: W2^T frags from L2, butterfly reduce ----
    float cp[16];
#pragma unroll
    for (int c = 0; c < 16; c++) cp[c] = 0.f;
#pragma unroll
    for (int h = 0; h < 4; h++) {
        const unsigned short* wrow = W2tb + (h * 64 + dg * 8 + eg) * 16;
        ushort8 wlo = *(const ushort8*)wrow;
        ushort8 whi = *(const ushort8*)(wrow + 8);
        float ov = outv[h];
#pragma unroll
        for (int c = 0; c < 8; c++) {
            cp[c] = fmaf(ov, bf2f(wlo[c]), cp[c]);
            cp[8 + c] = fmaf(ov, bf2f(whi[c]), cp[8 + c]);
        }
    }
    bool t0 = (lane & 1) != 0, t1 = (lane & 2) != 0, t2 = (lane & 4) != 0, t3 = (lane & 8) != 0;
    float p8[8];
#pragma unroll
    for (int q = 0; q < 8; q++) {
        float keep = t0 ? cp[8 + q] : cp[q];
        float send = t0 ? cp[q] : cp[8 + q];
        p8[q] = keep + __shfl_xor(send, 1);
    }
    float p4[4];
#pragma unroll
    for (int q = 0; q < 4; q++) {
        float keep = t1 ? p8[4 + q] : p8[q];
        float send = t1 ? p8[q] : p8[4 + q];
        p4[q] = keep + __shfl_xor(send, 2);
    }
    float p2[2];
#pragma unroll
    for (int q = 0; q < 2; q++) {
        float keep = t2 ? p4[2 + q] : p4[q];
        float send = t2 ? p4[q] : p4[2 + q];
        p2[q] = keep + __shfl_xor(send, 4);
    }
    float r = (t3 ? p2[1] : p2[0]) + __shfl_xor(t3 ? p2[0] : p2[1], 8);
    r += __shfl_xor(r, 16);
    r += __shfl_xor(r, 32);
    int c = ((lane & 1) << 3) | ((lane & 2) << 1) | ((lane & 4) >> 1) | ((lane & 8) >> 3);
    float rr = r + b2g[c];
    if (lane < 16) h2[(size_t)n * NCLASS + c] = rr;
    float q1 = rr * a2[c], q2 = rr * a2[NCLASS + c];
#pragma unroll
    for (int o = 1; o < 64; o <<= 1) {
        q1 += __shfl_xor(q1, o);
        q2 += __shfl_xor(q2, o);
    }
    if (lane == 0) { as2[n] = q1 * 0.25f; at2[n] = q2 * 0.25f; }
}

// agg2: one WAVE per row, packed dense (no dup pass), fused log_softmax.
__global__ void agg2(const float* __restrict__ h2, const float* __restrict__ as2,
                     const float* __restrict__ at2, const int* __restrict__ degv,
                     const int* __restrict__ dense, float* __restrict__ out) {
    __shared__ int tf[4][MAXDEG];
    __shared__ float pf[4][MAXDEG];
    int wv = threadIdx.x >> 6, lane = threadIdx.x & 63;
    int n = blockIdx.x * 4 + wv;
    int deg = degv[n];
    if (deg > MAXDEG) deg = MAXDEG;
    if (deg == 0) {
        if (lane < NCLASS) out[(size_t)n * NCLASS + lane] = -logf((float)NCLASS);
        return;
    }
    const int* drow = dense + (size_t)n * MAXDEG;
    float asvn = as2[n];
    int jg = lane >> 2, cq = lane & 3;
    if (deg <= 64) {
        int pk = (lane < deg) ? drow[lane] : -1;
        int t = 0;
        float p = -INFINITY;
        if (pk >= 0) {
            t = pk & 0xFFFF;
            float e = asvn + at2[t];
            e = e > 0.f ? e : LRELU_ALPHA * e;
            p = (float)(pk >> 16) * e;
        }
        float m = p;
#pragma unroll
        for (int o = 32; o >= 1; o >>= 1) m = fmaxf(m, __shfl_xor(m, o));
        float pe = expf(p - m);
        float s = pe;
#pragma unroll
        for (int o = 32; o >= 1; o >>= 1) s += __shfl_xor(s, o);
        float4 a4 = {0.f, 0.f, 0.f, 0.f};
#pragma unroll
        for (int i = 0; i < 4; i++) {
            int j = i * 16 + jg;
            float pj = __shfl(pe, j);
            int tjv = __shfl(t, j);
            float4 hv = *(const float4*)(h2 + (size_t)tjv * NCLASS + cq * 4);
            a4.x += pj * hv.x; a4.y += pj * hv.y;
            a4.z += pj * hv.z; a4.w += pj * hv.w;
        }
#pragma unroll
        for (int o = 4; o <= 32; o <<= 1) {
            a4.x += __shfl_xor(a4.x, o);
            a4.y += __shfl_xor(a4.y, o);
            a4.z += __shfl_xor(a4.z, o);
            a4.w += __shfl_xor(a4.w, o);
        }
        float inv = 1.f / s;
        float4 v4 = {a4.x * inv, a4.y * inv, a4.z * inv, a4.w * inv};
        float mm = fmaxf(fmaxf(v4.x, v4.y), fmaxf(v4.z, v4.w));
        mm = fmaxf(mm, __shfl_xor(mm, 1));
        mm = fmaxf(mm, __shfl_xor(mm, 2));
        float se = expf(v4.x - mm) + expf(v4.y - mm) + expf(v4.z - mm) + expf(v4.w - mm);
        se += __shfl_xor(se, 1);
        se += __shfl_xor(se, 2);
        float lse = mm + logf(se);
        if (jg == 0) {
            float4 o4 = {v4.x - lse, v4.y - lse, v4.z - lse, v4.w - lse};
            *(float4*)(out + (size_t)n * NCLASS + cq * 4) = o4;
        }
    } else {
        for (int j = lane; j < deg; j += 64) {
            int pk = drow[j];
            if (pk < 0) {
                tf[wv][j] = 0;
                pf[wv][j] = -INFINITY;
            } else {
                int t = pk & 0xFFFF;
                tf[wv][j] = t;
                float e = asvn + at2[t];
                e = e > 0.f ? e : LRELU_ALPHA * e;
                pf[wv][j] = (float)(pk >> 16) * e;
            }
        }
        float m = -INFINITY;
        for (int j = lane; j < deg; j += 64) m = fmaxf(m, pf[wv][j]);
#pragma unroll
        for (int o = 32; o >= 1; o >>= 1) m = fmaxf(m, __shfl_xor(m, o));
        float s = 0.f;
        for (int j = lane; j < deg; j += 64) {
            float pe = expf(pf[wv][j] - m);
            pf[wv][j] = pe;
            s += pe;
        }
#pragma unroll
        for (int o = 32; o >= 1; o >>= 1) s += __shfl_xor(s, o);
        float4 a4 = {0.f, 0.f, 0.f, 0.f};
        for (int j = jg; j < deg; j += 16) {
            float pj = pf[wv][j];
            float4 hv = *(const float4*)(h2 + (size_t)tf[wv][j] * NCLASS + cq * 4);
            a4.x += pj * hv.x; a4.y += pj * hv.y;
            a4.z += pj * hv.z; a4.w += pj * hv.w;
        }
#pragma unroll
        for (int o = 4; o <= 32; o <<= 1) {
            a4.x += __shfl_xor(a4.x, o);
            a4.y += __shfl_xor(a4.y, o);
            a4.z += __shfl_xor(a4.z, o);
            a4.w += __shfl_xor(a4.w, o);
        }
        float inv = 1.f / s;
        float4 v4 = {a4.x * inv, a4.y * inv, a4.z * inv, a4.w * inv};
        float mm = fmaxf(fmaxf(v4.x, v4.y), fmaxf(v4.z, v4.w));
        mm = fmaxf(mm, __shfl_xor(mm, 1));
        mm = fmaxf(mm, __shfl_xor(mm, 2));
        float se = expf(v4.x - mm) + expf(v4.y - mm) + expf(v4.z - mm) + expf(v4.w - mm);
        se += __shfl_xor(se, 1);
        se += __shfl_xor(se, 2);
        float lse = mm + logf(se);
        if (jg == 0) {
            float4 o4 = {v4.x - lse, v4.y - lse, v4.z - lse, v4.w - lse};
            *(float4*)(out + (size_t)n * NCLASS + cq * 4) = o4;
        }
    }
}

extern "C" void kernel_launch(void* const* d_in, const int* in_sizes, int n_in,
                              void* d_out, int out_size, void* d_ws, size_t ws_size,
                              hipStream_t stream) {
    const float* x  = (const float*)d_in[0];
    const int* el   = (const int*)d_in[1];
    const float* W1 = (const float*)d_in[2];
    const float* b1 = (const float*)d_in[3];
    const float* a1 = (const float*)d_in[4];
    const float* W2 = (const float*)d_in[5];
    const float* b2 = (const float*)d_in[6];
    const float* a2 = (const float*)d_in[7];
    float* out = (float*)d_out;

    unsigned short* h1b = (unsigned short*)d_ws;  // 4*8192*64 bf16 = 4 MB
    float* h2   = (float*)(h1b + 2097152);        // 8192*16 fp32
    float* as1  = h2 + 131072;                    // [n][4]
    float* at1  = as1 + 32768;                    // [n][4]
    float* as2  = at1 + 32768;
    float* at2  = as2 + 8192;
    int* deg    = (int*)(at2 + 8192);             // 8192
    int* dense  = deg + 8192;                     // 8192*128 = 4 MB
    unsigned short* Wbf  = (unsigned short*)(dense + 8192 * MAXDEG);  // 256 KB
    unsigned short* W2tb = Wbf + 131072;          // 256*16 bf16 = 8 KB

    const int* src = el;
    const int* tgt = el + NEDGE;

    prep<<<97, 256, 0, stream>>>(W1, Wbf, deg, W2, W2tb);
    gemm1c<<<1536, 256, 0, stream>>>(x, Wbf, b1, h1b, a1, as1, at1, src, tgt, deg, dense);
    agg1f<<<NN / 4, 256, 0, stream>>>(h1b, as1, at1, deg, dense, W2tb, b2, a2, h2, as2, at2);
    agg2<<<NN / 4, 256, 0, stream>>>(h2, as2, at2, deg, dense, out);
}